// Round 1
// baseline (73418.762 us; speedup 1.0000x reference)
//
#include <hip/hip_runtime.h>
#include <cstdint>
#include <cmath>

// TinyVanillaRNN: T=16384 sequential steps of h = tanh(U[:,x_t] + W h + bh),
// logits[t] = V h_t + by, out = [logits (T*O) | h_T (H)], all fp32.
//
// Latency-bound sequential recurrence. 32 blocks x 512 threads:
//   waves 0-3: own 32 rows of W entirely in VGPRs (128 VGPR/lane), compute
//              the matvec + tanh each step, publish their 8-row slice with a
//              per-wave agent-scope release flag; consumers spin on flags.
//   waves 4-7: own 16 rows of V in VGPRs (64 VGPR/lane), compute logits for
//              h_{t-1} (in LDS) concurrently with the step-t matvec -> the
//              output GEMM is fully hidden off the critical path.
// h ping-pongs through a global double buffer (d_ws); flags memset to -1.

constexpr int T_STEPS = 16384;
constexpr int D_DIM   = 512;
constexpr int H_DIM   = 1024;
constexpr int O_DIM   = 512;
constexpr int NBLK    = 32;
constexpr int NTHR    = 512;
constexpr int LSTR    = 136;   // 128-chunk padded to 136 floats: kills 8-way LDS bank conflicts

__global__ __launch_bounds__(NTHR, 2)
void rnn_fused(const int* __restrict__ xs, const float* __restrict__ h0,
               const float* __restrict__ U, const float* __restrict__ W,
               const float* __restrict__ V, const float* __restrict__ bh,
               const float* __restrict__ by, float* __restrict__ out,
               int* __restrict__ flags, float* __restrict__ hcur)
{
    const int b   = blockIdx.x;
    const int tid = threadIdx.x;

    __shared__ float hl[2][8 * LSTR];   // double-buffered padded copy of h_{t-1}

    // ---- per-thread setup ----
    float4 wreg[32];                    // waves 0-3: 128 floats of W row-chunk
    float4 vreg[16];                    // waves 4-7: 64 floats of V row-chunk
    float bh_r = 0.f, by_r = 0.f;
    int row = 0, p = 0, wv = 0;         // matvec role
    int vrow = 0, vpart = 0, vrowg = 0; // logits role

    if (tid < 256) {
        wv = tid >> 6;                  // wave 0..3
        const int lane = tid & 63;
        const int rl   = lane >> 3;     // row-in-wave 0..7
        p    = lane & 7;                // k-chunk 0..7 (128 floats each)
        row  = b * 32 + wv * 8 + rl;    // global W/h row
        const float* wp = W + (size_t)row * H_DIM + p * 128;
#pragma unroll
        for (int j = 0; j < 32; ++j) wreg[j] = ((const float4*)wp)[j];
        bh_r = bh[row];
    } else {
        const int ltid = tid - 256;
        vrow  = ltid >> 4;              // 0..15
        vpart = ltid & 15;              // 0..15 (64 k-elems, interleaved)
        vrowg = b * 16 + vrow;          // global V/logits row (col of out)
        const float* vp = V + (size_t)vrowg * H_DIM;
#pragma unroll
        for (int j = 0; j < 16; ++j)
            vreg[j] = *(const float4*)(vp + vpart * 4 + 64 * j);
        if (vpart == 0) by_r = by[vrowg];
    }

    float4 hstage = make_float4(0.f, 0.f, 0.f, 0.f);

    for (int t = 0; t < T_STEPS; ++t) {
        const int sb = 1 - (t & 1);     // LDS buffer that will hold h_{t-1}

        // prefetch (independent of the recurrence; overlaps the spin-wait)
        const int xt = xs[t];
        float uv = 0.f;
        if (tid < 256 && p == 0) uv = U[(size_t)row * D_DIM + xt];

        // wait for all 128 wave-slices of h_{t-1}
        if (t > 0 && tid < 128) {
            while (__hip_atomic_load(&flags[tid], __ATOMIC_RELAXED,
                                     __HIP_MEMORY_SCOPE_AGENT) < t - 1) { }
            __builtin_amdgcn_fence(__ATOMIC_ACQUIRE, "agent");
        }
        __syncthreads();   // barrier1: flags seen; logits(t-2) finished with hl[sb]

        if (tid < 256) {   // stage h_{t-1} -> LDS (padded layout)
            const float* src = (t == 0) ? (h0 + tid * 4)
                                        : (hcur + (size_t)((t - 1) & 1) * H_DIM + tid * 4);
            hstage = *(const float4*)src;
            const int chunk = tid >> 5;
            const int off   = (tid & 31) * 4;
            *(float4*)&hl[sb][chunk * LSTR + off] = hstage;
        }
        __syncthreads();   // barrier2: h_{t-1} staged

        if (tid < 256) {
            // ---- critical path: 32-row matvec, tanh, publish ----
            const float* hp = &hl[sb][p * LSTR];
            float4 a0 = make_float4(0.f, 0.f, 0.f, 0.f);
            float4 a1 = make_float4(0.f, 0.f, 0.f, 0.f);
#pragma unroll
            for (int j = 0; j < 32; j += 2) {
                const float4 ha = *(const float4*)(hp + 4 * j);
                const float4 hb = *(const float4*)(hp + 4 * j + 4);
                a0.x += wreg[j].x * ha.x;  a0.y += wreg[j].y * ha.y;
                a0.z += wreg[j].z * ha.z;  a0.w += wreg[j].w * ha.w;
                a1.x += wreg[j+1].x * hb.x;  a1.y += wreg[j+1].y * hb.y;
                a1.z += wreg[j+1].z * hb.z;  a1.w += wreg[j+1].w * hb.w;
            }
            float sum = (a0.x + a0.y) + (a0.z + a0.w)
                      + (a1.x + a1.y) + (a1.z + a1.w);
            sum += __shfl_xor(sum, 1);
            sum += __shfl_xor(sum, 2);
            sum += __shfl_xor(sum, 4);
            if (p == 0) {
                const float hv = tanhf(sum + bh_r + uv);
                hcur[(size_t)(t & 1) * H_DIM + row] = hv;
            }
            if ((tid & 63) == 0) {      // wave leader: release this wave's 8 rows
                __hip_atomic_store(&flags[b * 4 + wv], t, __ATOMIC_RELEASE,
                                   __HIP_MEMORY_SCOPE_AGENT);
            }
        } else if (t >= 1) {
            // ---- hidden: logits row t-1 from hl[sb] ----
            float sum = 0.f;
#pragma unroll
            for (int j = 0; j < 16; ++j) {
                const int k = vpart * 4 + 64 * j;
                const float4 h4 = *(const float4*)&hl[sb][(k >> 7) * LSTR + (k & 127)];
                sum += vreg[j].x * h4.x + vreg[j].y * h4.y
                     + vreg[j].z * h4.z + vreg[j].w * h4.w;
            }
            sum += __shfl_xor(sum, 1);
            sum += __shfl_xor(sum, 2);
            sum += __shfl_xor(sum, 4);
            sum += __shfl_xor(sum, 8);
            if (vpart == 0) out[(size_t)(t - 1) * O_DIM + vrowg] = sum + by_r;
        }
    }

    // ---- epilogue: logits(T-1) and h_T ----
    if (tid < 128) {
        while (__hip_atomic_load(&flags[tid], __ATOMIC_RELAXED,
                                 __HIP_MEMORY_SCOPE_AGENT) < T_STEPS - 1) { }
        __builtin_amdgcn_fence(__ATOMIC_ACQUIRE, "agent");
    }
    __syncthreads();
    const int sbE = 1 - (T_STEPS & 1);
    if (tid < 256) {
        hstage = *(const float4*)(hcur + (size_t)((T_STEPS - 1) & 1) * H_DIM + tid * 4);
        const int chunk = tid >> 5;
        const int off   = (tid & 31) * 4;
        *(float4*)&hl[sbE][chunk * LSTR + off] = hstage;
    }
    __syncthreads();
    if (tid < 256) {
        // h_T output (fp32), straight from the staged registers
        *(float4*)&out[(size_t)T_STEPS * O_DIM + tid * 4] = hstage;
    } else {
        float sum = 0.f;
#pragma unroll
        for (int j = 0; j < 16; ++j) {
            const int k = vpart * 4 + 64 * j;
            const float4 h4 = *(const float4*)&hl[sbE][(k >> 7) * LSTR + (k & 127)];
            sum += vreg[j].x * h4.x + vreg[j].y * h4.y
                 + vreg[j].z * h4.z + vreg[j].w * h4.w;
        }
        sum += __shfl_xor(sum, 1);
        sum += __shfl_xor(sum, 2);
        sum += __shfl_xor(sum, 4);
        sum += __shfl_xor(sum, 8);
        if (vpart == 0) out[(size_t)(T_STEPS - 1) * O_DIM + vrowg] = sum + by_r;
    }
}

extern "C" void kernel_launch(void* const* d_in, const int* in_sizes, int n_in,
                              void* d_out, int out_size, void* d_ws, size_t ws_size,
                              hipStream_t stream) {
    const int*   xs = (const int*)d_in[0];
    const float* h0 = (const float*)d_in[1];
    const float* U  = (const float*)d_in[2];
    const float* W  = (const float*)d_in[3];
    const float* V  = (const float*)d_in[4];
    const float* bh = (const float*)d_in[5];
    const float* by = (const float*)d_in[6];
    float* out = (float*)d_out;

    // ws layout: [flags: 128 ints][hcur: 2*1024 floats]
    int*   flags = (int*)d_ws;
    float* hcur  = (float*)((char*)d_ws + 512);

    hipMemsetAsync(d_ws, 0xFF, 512, stream);   // flags = -1 (don't rely on poison)
    rnn_fused<<<NBLK, NTHR, 0, stream>>>(xs, h0, U, W, V, bh, by, out, flags, hcur);
}

// Round 2
// 30854.755 us; speedup vs baseline: 2.3795x; 2.3795x over previous
//
#include <hip/hip_runtime.h>
#include <cstdint>

// TinyVanillaRNN: T=16384 sequential steps h = tanh(U[:,x_t] + W h + bh);
// logits[t] = V h_t + by. out = [logits (T*O) | h_T (H)], fp32.
//
// R2: single-atomic tagged handoff. h_t is published as 1024 u64 words
// (step_tag<<32 | f32_bits), double-buffered by step parity. Consumers poll
// the payload directly: no flag indirection, no release-ack, no separate h
// load -> one fabric visibility latency per step instead of ~4.
// 32 blocks x 512 thr: waves 0-3 hold 32 W rows in VGPRs (matvec+tanh+publish),
// waves 4-7 hold 16 V rows and compute logits[t-1] concurrently (hidden).
// One __syncthreads per step (LDS h double-buffer makes the 2nd redundant).

constexpr int T_STEPS = 16384;
constexpr int D_DIM   = 512;
constexpr int H_DIM   = 1024;
constexpr int O_DIM   = 512;
constexpr int NBLK    = 32;
constexpr int NTHR    = 512;
constexpr int LSTR    = 132;   // chunk pad 128->132: p*132%32 = 4p -> 8 disjoint 4-bank groups

__device__ __forceinline__ float fast_tanh(float x) {
    // 1 - 2/(e^{2x}+1); exp overflow -> inf -> 1.0, underflow -> 0 -> -1.0 (both exact)
    float e = __expf(2.f * x);
    return 1.f - 2.f / (e + 1.f);
}

__global__ __launch_bounds__(NTHR, 2)
void rnn_fused(const int* __restrict__ xs, const float* __restrict__ h0,
               const float* __restrict__ U, const float* __restrict__ W,
               const float* __restrict__ V, const float* __restrict__ bh,
               const float* __restrict__ by, float* __restrict__ out,
               unsigned long long* __restrict__ htag)
{
    const int b   = blockIdx.x;
    const int tid = threadIdx.x;

    __shared__ float hl[2][8 * LSTR];   // double-buffered padded h_{t-1}

    float4 wreg[32];                    // waves 0-3: 128 floats of a W row-chunk
    float4 vreg[16];                    // waves 4-7: 64 floats of a V row-chunk
    float bh_r = 0.f, by_r = 0.f;
    int row = 0, p = 0;                 // matvec role
    int vpart = 0, vrowg = 0;           // logits role

    if (tid < 256) {
        const int wv   = tid >> 6;
        const int lane = tid & 63;
        const int rl   = lane >> 3;     // row-in-wave 0..7
        p   = lane & 7;                 // k-chunk 0..7 (128 floats)
        row = b * 32 + wv * 8 + rl;
        const float* wp = W + (size_t)row * H_DIM + p * 128;
#pragma unroll
        for (int j = 0; j < 32; ++j) wreg[j] = ((const float4*)wp)[j];
        bh_r = bh[row];
    } else {
        const int ltid = tid - 256;
        vpart = ltid & 15;              // 0..15
        vrowg = b * 16 + (ltid >> 4);   // global logits column
        const float* vp = V + (size_t)vrowg * H_DIM;
#pragma unroll
        for (int j = 0; j < 16; ++j)
            vreg[j] = *(const float4*)(vp + vpart * 4 + 64 * j);
        if (vpart == 0) by_r = by[vrowg];
    }

    for (int t = 0; t < T_STEPS; ++t) {
        const int sb = (~t) & 1;        // LDS buffer receiving h_{t-1}

        float uv = 0.f;
        if (tid < 256) {
            if (p == 0)                 // issued before the poll -> latency hidden
                uv = U[(size_t)row * D_DIM + xs[t]];

            // ---- acquire h_{t-1}: poll tagged payload directly ----
            float4 h4;
            if (t == 0) {
                h4 = *(const float4*)(h0 + tid * 4);
            } else {
                const unsigned long long want = (unsigned long long)(unsigned)(t - 1);
                const unsigned long long* src =
                    htag + (size_t)((t - 1) & 1) * H_DIM + tid * 4;
                unsigned long long q0, q1, q2, q3;
                do {
                    q0 = __hip_atomic_load(src + 0, __ATOMIC_RELAXED, __HIP_MEMORY_SCOPE_AGENT);
                    q1 = __hip_atomic_load(src + 1, __ATOMIC_RELAXED, __HIP_MEMORY_SCOPE_AGENT);
                    q2 = __hip_atomic_load(src + 2, __ATOMIC_RELAXED, __HIP_MEMORY_SCOPE_AGENT);
                    q3 = __hip_atomic_load(src + 3, __ATOMIC_RELAXED, __HIP_MEMORY_SCOPE_AGENT);
                } while ((q0 >> 32) != want || (q1 >> 32) != want ||
                         (q2 >> 32) != want || (q3 >> 32) != want);
                h4 = make_float4(__uint_as_float((unsigned)q0),
                                 __uint_as_float((unsigned)q1),
                                 __uint_as_float((unsigned)q2),
                                 __uint_as_float((unsigned)q3));
            }
            *(float4*)&hl[sb][(tid >> 5) * LSTR + (tid & 31) * 4] = h4;
        }
        __syncthreads();   // the only barrier per step

        if (tid < 256) {
            // ---- critical path: 32-row matvec, tanh, publish ----
            const float* hp = &hl[sb][p * LSTR];
            float4 a0 = make_float4(0.f, 0.f, 0.f, 0.f);
            float4 a1 = make_float4(0.f, 0.f, 0.f, 0.f);
#pragma unroll
            for (int j = 0; j < 32; j += 2) {
                const float4 ha = *(const float4*)(hp + 4 * j);
                const float4 hb = *(const float4*)(hp + 4 * j + 4);
                a0.x += wreg[j].x * ha.x;    a0.y += wreg[j].y * ha.y;
                a0.z += wreg[j].z * ha.z;    a0.w += wreg[j].w * ha.w;
                a1.x += wreg[j+1].x * hb.x;  a1.y += wreg[j+1].y * hb.y;
                a1.z += wreg[j+1].z * hb.z;  a1.w += wreg[j+1].w * hb.w;
            }
            float sum = (a0.x + a0.y) + (a0.z + a0.w)
                      + (a1.x + a1.y) + (a1.z + a1.w);
            sum += __shfl_xor(sum, 1);
            sum += __shfl_xor(sum, 2);
            sum += __shfl_xor(sum, 4);
            if (p == 0) {
                const float hv = fast_tanh(sum + bh_r + uv);
                const unsigned long long pk =
                    ((unsigned long long)(unsigned)t << 32) | (unsigned long long)__float_as_uint(hv);
                __hip_atomic_store(htag + (size_t)(t & 1) * H_DIM + row, pk,
                                   __ATOMIC_RELAXED, __HIP_MEMORY_SCOPE_AGENT);
            }
        } else if (t >= 1) {
            // ---- hidden: logits row t-1 ----
            float sum = 0.f;
#pragma unroll
            for (int j = 0; j < 16; ++j) {
                const int k = vpart * 4 + 64 * j;
                const float4 h4 = *(const float4*)&hl[sb][(k >> 7) * LSTR + (k & 127)];
                sum += vreg[j].x * h4.x + vreg[j].y * h4.y
                     + vreg[j].z * h4.z + vreg[j].w * h4.w;
            }
            sum += __shfl_xor(sum, 1);
            sum += __shfl_xor(sum, 2);
            sum += __shfl_xor(sum, 4);
            sum += __shfl_xor(sum, 8);
            if (vpart == 0) out[(size_t)(t - 1) * O_DIM + vrowg] = sum + by_r;
        }
    }

    // ---- epilogue: logits[T-1] and h_T (h_{T-1} has tag T-1, parity 1) ----
    const int sbE = (~T_STEPS) & 1;     // = 1, free (hl[1] last read at t=T-2)
    if (tid < 256) {
        const unsigned long long want = (unsigned long long)(unsigned)(T_STEPS - 1);
        const unsigned long long* src =
            htag + (size_t)((T_STEPS - 1) & 1) * H_DIM + tid * 4;
        unsigned long long q0, q1, q2, q3;
        do {
            q0 = __hip_atomic_load(src + 0, __ATOMIC_RELAXED, __HIP_MEMORY_SCOPE_AGENT);
            q1 = __hip_atomic_load(src + 1, __ATOMIC_RELAXED, __HIP_MEMORY_SCOPE_AGENT);
            q2 = __hip_atomic_load(src + 2, __ATOMIC_RELAXED, __HIP_MEMORY_SCOPE_AGENT);
            q3 = __hip_atomic_load(src + 3, __ATOMIC_RELAXED, __HIP_MEMORY_SCOPE_AGENT);
        } while ((q0 >> 32) != want || (q1 >> 32) != want ||
                 (q2 >> 32) != want || (q3 >> 32) != want);
        float4 h4 = make_float4(__uint_as_float((unsigned)q0),
                                __uint_as_float((unsigned)q1),
                                __uint_as_float((unsigned)q2),
                                __uint_as_float((unsigned)q3));
        *(float4*)&hl[sbE][(tid >> 5) * LSTR + (tid & 31) * 4] = h4;
        if (b == 0)   // h_T output, written once
            *(float4*)&out[(size_t)T_STEPS * O_DIM + tid * 4] = h4;
    }
    __syncthreads();
    if (tid >= 256) {
        float sum = 0.f;
#pragma unroll
        for (int j = 0; j < 16; ++j) {
            const int k = vpart * 4 + 64 * j;
            const float4 h4 = *(const float4*)&hl[sbE][(k >> 7) * LSTR + (k & 127)];
            sum += vreg[j].x * h4.x + vreg[j].y * h4.y
                 + vreg[j].z * h4.z + vreg[j].w * h4.w;
        }
        sum += __shfl_xor(sum, 1);
        sum += __shfl_xor(sum, 2);
        sum += __shfl_xor(sum, 4);
        sum += __shfl_xor(sum, 8);
        if (vpart == 0) out[(size_t)(T_STEPS - 1) * O_DIM + vrowg] = sum + by_r;
    }
}

extern "C" void kernel_launch(void* const* d_in, const int* in_sizes, int n_in,
                              void* d_out, int out_size, void* d_ws, size_t ws_size,
                              hipStream_t stream) {
    const int*   xs = (const int*)d_in[0];
    const float* h0 = (const float*)d_in[1];
    const float* U  = (const float*)d_in[2];
    const float* W  = (const float*)d_in[3];
    const float* V  = (const float*)d_in[4];
    const float* bh = (const float*)d_in[5];
    const float* by = (const float*)d_in[6];
    float* out = (float*)d_out;

    // ws: htag[2][1024] u64. Poison 0xAAAAAAAA tag never equals a valid step,
    // but memset anyway so we don't depend on harness re-poisoning semantics.
    unsigned long long* htag = (unsigned long long*)d_ws;
    hipMemsetAsync(d_ws, 0xAA, 2 * H_DIM * sizeof(unsigned long long), stream);

    rnn_fused<<<NBLK, NTHR, 0, stream>>>(xs, h0, U, W, V, bh, by, out, htag);
}

// Round 3
// 22865.396 us; speedup vs baseline: 3.2109x; 1.3494x over previous
//
#include <hip/hip_runtime.h>
#include <cstdint>

// TinyVanillaRNN: T=16384 sequential steps h = tanh(U[:,x_t] + W h + bh);
// logits[t] = V h_t + by. out = [logits (T*O) | h_T (H)], fp32.
//
// R3: minimize critical-path LDS delivery. 32 blocks x 512 threads.
// Fragment: thread = 4 W-rows x 16 k's (64 W floats in VGPRs) -> fetches only
// 16 h floats/step (4x ds_read_b128 at delivery floor). Reduce = 7-shuffle
// fused select+butterfly (row sum lands on lane l&3). V tiled identically
// (2 rows x 16 k's): logits reuse the matvec h registers -> zero extra LDS,
// computed in the post-publish window (hidden under next poll RTT).
// Handoff: tagged u64 (step<<32 | f32 bits), parity double buffer, relaxed
// agent atomics; all 512 threads poll 2 words each.

constexpr int T_STEPS = 16384;
constexpr int D_DIM   = 512;
constexpr int H_DIM   = 1024;
constexpr int O_DIM   = 512;
constexpr int NBLK    = 32;
constexpr int NTHR    = 512;

__device__ __forceinline__ float fast_tanh(float x) {
    // 1 - 2/(e^{2x}+1); saturates exactly at +-1 for large |x|
    float e = __expf(2.f * x);
    return 1.f - 2.f / (e + 1.f);
}

__device__ __forceinline__ float hsum4(const float4& v) {
    return (v.x + v.y) + (v.z + v.w);
}

__global__ __launch_bounds__(NTHR, 2)
void rnn_fused(const int* __restrict__ xs, const float* __restrict__ h0,
               const float* __restrict__ U, const float* __restrict__ W,
               const float* __restrict__ V, const float* __restrict__ bh,
               const float* __restrict__ by, float* __restrict__ out,
               unsigned long long* __restrict__ htag)
{
    const int b   = blockIdx.x;
    const int tid = threadIdx.x;
    const int w   = tid >> 6;      // wave 0..7
    const int l   = tid & 63;      // lane

    // h in LDS: 64 chunks x 16 floats; quad q of chunk c stored at dword
    // 16c + 4*(q ^ ((c>>1)&3))  (swizzle is a permutation inside the 64B
    // chunk -> no padding; spreads reads over all 32 banks).
    __shared__ float hl[2][H_DIM];

    // ---- W fragment: rows wr0..wr0+3, k in [16l, 16l+16) ----
    const int wr0 = b * 32 + w * 4;
    float4 wreg[4][4];
#pragma unroll
    for (int j = 0; j < 4; ++j)
#pragma unroll
        for (int q = 0; q < 4; ++q)
            wreg[j][q] = *(const float4*)(W + (size_t)(wr0 + j) * H_DIM + 16 * l + 4 * q);
    const float bh_r = bh[wr0 + (l & 3)];
    const int   urow = wr0 + (l & 3);

    // ---- V fragment: rows vr0, vr0+1, same k-chunk ----
    const int vr0 = b * 16 + w * 2;
    float4 vreg[2][4];
#pragma unroll
    for (int m = 0; m < 2; ++m)
#pragma unroll
        for (int q = 0; q < 4; ++q)
            vreg[m][q] = *(const float4*)(V + (size_t)(vr0 + m) * H_DIM + 16 * l + 4 * q);
    const float by_r = by[vr0 + (l & 1)];

    // ---- LDS addresses (dwords) ----
    int rdw[4];                    // lane reads chunk l, logical quads 0..3
#pragma unroll
    for (int q = 0; q < 4; ++q)
        rdw[q] = 16 * l + 4 * (q ^ ((l >> 1) & 3));
    const int c   = tid >> 3;                       // staged chunk
    const int qw  = (tid >> 1) & 3;                 // staged quad
    const int wdw = 16 * c + 4 * (qw ^ ((c >> 1) & 3)) + 2 * (tid & 1);  // even -> 8B aligned

    const bool o1 = (l & 1) != 0, o2 = (l & 2) != 0;

    for (int t = 0; t < T_STEPS; ++t) {
        const int sb = (~t) & 1;
        float* hb = hl[sb];

        // independent prefetch chain: xs[t] -> U gather (hidden under poll)
        const int   xt = xs[t];
        const float uv = U[(size_t)urow * D_DIM + xt];

        // ---- acquire h^{(t)}: all 512 threads poll 2 tagged words ----
        float2 hpair;
        if (t == 0) {
            hpair = *(const float2*)(h0 + 2 * tid);
        } else {
            const unsigned want = (unsigned)(t - 1);
            const unsigned long long* pp = htag + (size_t)((t - 1) & 1) * H_DIM + 2 * tid;
            unsigned long long q0, q1;
            do {
                q0 = __hip_atomic_load(pp + 0, __ATOMIC_RELAXED, __HIP_MEMORY_SCOPE_AGENT);
                q1 = __hip_atomic_load(pp + 1, __ATOMIC_RELAXED, __HIP_MEMORY_SCOPE_AGENT);
            } while ((unsigned)(q0 >> 32) != want || (unsigned)(q1 >> 32) != want);
            hpair = make_float2(__uint_as_float((unsigned)q0),
                                __uint_as_float((unsigned)q1));
        }
        *(float2*)&hb[wdw] = hpair;
        __syncthreads();

        // ---- critical path: 16 h floats, 64 FMAs, fused select+reduce ----
        float4 h4[4];
#pragma unroll
        for (int q = 0; q < 4; ++q) h4[q] = *(const float4*)&hb[rdw[q]];

        float s[4];
#pragma unroll
        for (int j = 0; j < 4; ++j) {
            float4 a = make_float4(0.f, 0.f, 0.f, 0.f);
#pragma unroll
            for (int q = 0; q < 4; ++q) {
                a.x += wreg[j][q].x * h4[q].x;
                a.y += wreg[j][q].y * h4[q].y;
                a.z += wreg[j][q].z * h4[q].z;
                a.w += wreg[j][q].w * h4[q].w;
            }
            s[j] = hsum4(a);
        }
        // select+butterfly: lane l ends with full sum of row wr0 + (l&3)
        float A  = o1 ? s[1] : s[0], Ax = o1 ? s[0] : s[1];
        float B  = o1 ? s[3] : s[2], Bx = o1 ? s[2] : s[3];
        A += __shfl_xor(Ax, 1);
        B += __shfl_xor(Bx, 1);
        float Cv = o2 ? B : A, Cx = o2 ? A : B;
        Cv += __shfl_xor(Cx, 2);
        Cv += __shfl_xor(Cv, 4);
        Cv += __shfl_xor(Cv, 8);
        Cv += __shfl_xor(Cv, 16);
        Cv += __shfl_xor(Cv, 32);

        const float hv = fast_tanh(Cv + bh_r + uv);
        if (l < 4) {
            const unsigned long long pk =
                ((unsigned long long)(unsigned)t << 32) | (unsigned long long)__float_as_uint(hv);
            __hip_atomic_store(htag + (size_t)(t & 1) * H_DIM + wr0 + l, pk,
                               __ATOMIC_RELAXED, __HIP_MEMORY_SCOPE_AGENT);
        }

        // ---- hidden window: logits[t-1] from h4 registers (h^{(t)}) ----
        if (t > 0) {
            float sv[2];
#pragma unroll
            for (int m = 0; m < 2; ++m) {
                float4 a = make_float4(0.f, 0.f, 0.f, 0.f);
#pragma unroll
                for (int q = 0; q < 4; ++q) {
                    a.x += vreg[m][q].x * h4[q].x;
                    a.y += vreg[m][q].y * h4[q].y;
                    a.z += vreg[m][q].z * h4[q].z;
                    a.w += vreg[m][q].w * h4[q].w;
                }
                sv[m] = hsum4(a);
            }
            float P  = o1 ? sv[1] : sv[0], Px = o1 ? sv[0] : sv[1];
            P += __shfl_xor(Px, 1);
            P += __shfl_xor(P, 2);
            P += __shfl_xor(P, 4);
            P += __shfl_xor(P, 8);
            P += __shfl_xor(P, 16);
            P += __shfl_xor(P, 32);
            if (l < 2) out[(size_t)(t - 1) * O_DIM + vr0 + l] = P + by_r;
        }
    }

    // ---- epilogue: h_T (tag T-1, parity 1) -> out tail + logits[T-1] ----
    {
        const unsigned want = (unsigned)(T_STEPS - 1);
        const unsigned long long* pp = htag + (size_t)((T_STEPS - 1) & 1) * H_DIM + 2 * tid;
        unsigned long long q0, q1;
        do {
            q0 = __hip_atomic_load(pp + 0, __ATOMIC_RELAXED, __HIP_MEMORY_SCOPE_AGENT);
            q1 = __hip_atomic_load(pp + 1, __ATOMIC_RELAXED, __HIP_MEMORY_SCOPE_AGENT);
        } while ((unsigned)(q0 >> 32) != want || (unsigned)(q1 >> 32) != want);
        float2 hpair = make_float2(__uint_as_float((unsigned)q0),
                                   __uint_as_float((unsigned)q1));
        if (b == 0)
            *(float2*)&out[(size_t)T_STEPS * O_DIM + 2 * tid] = hpair;

        float* hb = hl[1];             // free: loop's last stage used hl[0]
        *(float2*)&hb[wdw] = hpair;
        __syncthreads();
        float4 h4[4];
#pragma unroll
        for (int q = 0; q < 4; ++q) h4[q] = *(const float4*)&hb[rdw[q]];
        float sv[2];
#pragma unroll
        for (int m = 0; m < 2; ++m) {
            float4 a = make_float4(0.f, 0.f, 0.f, 0.f);
#pragma unroll
            for (int q = 0; q < 4; ++q) {
                a.x += vreg[m][q].x * h4[q].x;
                a.y += vreg[m][q].y * h4[q].y;
                a.z += vreg[m][q].z * h4[q].z;
                a.w += vreg[m][q].w * h4[q].w;
            }
            sv[m] = hsum4(a);
        }
        float P  = o1 ? sv[1] : sv[0], Px = o1 ? sv[0] : sv[1];
        P += __shfl_xor(Px, 1);
        P += __shfl_xor(P, 2);
        P += __shfl_xor(P, 4);
        P += __shfl_xor(P, 8);
        P += __shfl_xor(P, 16);
        P += __shfl_xor(P, 32);
        if (l < 2) out[(size_t)(T_STEPS - 1) * O_DIM + vr0 + l] = P + by_r;
    }
}

extern "C" void kernel_launch(void* const* d_in, const int* in_sizes, int n_in,
                              void* d_out, int out_size, void* d_ws, size_t ws_size,
                              hipStream_t stream) {
    const int*   xs = (const int*)d_in[0];
    const float* h0 = (const float*)d_in[1];
    const float* U  = (const float*)d_in[2];
    const float* W  = (const float*)d_in[3];
    const float* V  = (const float*)d_in[4];
    const float* bh = (const float*)d_in[5];
    const float* by = (const float*)d_in[6];
    float* out = (float*)d_out;

    // ws: htag[2][1024] u64. Poison tag 0xAAAAAAAA never matches a step in
    // [0,16384); memset keeps us independent of harness poison semantics.
    unsigned long long* htag = (unsigned long long*)d_ws;
    hipMemsetAsync(d_ws, 0xAA, 2 * H_DIM * sizeof(unsigned long long), stream);

    rnn_fused<<<NBLK, NTHR, 0, stream>>>(xs, h0, U, W, V, bh, by, out, htag);
}